// Round 1
// baseline (234.765 us; speedup 1.0000x reference)
//
#include <hip/hip_runtime.h>
#include <hip/hip_fp16.h>

// Problem constants
#define BB 4
#define NN 8192
#define DD 256
#define HH 8
#define MM 32768   // BB*NN

typedef __attribute__((ext_vector_type(8))) _Float16 half8;
typedef __attribute__((ext_vector_type(4))) float f32x4;

// ---------------- K0: conversions ----------------
__global__ void __launch_bounds__(256) k_cvt_x(const float* __restrict__ x,
                                               _Float16* __restrict__ x16) {
  size_t base = ((size_t)blockIdx.x * 256 + threadIdx.x) * 8;
  float4 a = *(const float4*)(x + base);
  float4 b = *(const float4*)(x + base + 4);
  half8 h;
  h[0] = (_Float16)a.x; h[1] = (_Float16)a.y; h[2] = (_Float16)a.z; h[3] = (_Float16)a.w;
  h[4] = (_Float16)b.x; h[5] = (_Float16)b.y; h[6] = (_Float16)b.z; h[7] = (_Float16)b.w;
  *(half8*)(x16 + base) = h;
}

// W_qkv [256][1536] fp32 -> Wt [1536][256] fp16 (transposed)
__global__ void __launch_bounds__(256) k_cvt_w(const float* __restrict__ w,
                                               _Float16* __restrict__ wt) {
  int idx = blockIdx.x * 256 + threadIdx.x;  // 0..393215
  int k = idx / 1536, c = idx % 1536;
  wt[(size_t)c * 256 + k] = (_Float16)w[idx];
}

// ---------------- K1: qkv GEMM + norm + rotary epilogue ----------------
// grid(8 heads, 512 rowtiles), 256 threads. Tile: 64 rows x 192 cols (q_h|k_h|v_h).
__global__ void __launch_bounds__(256) k_qkv(const _Float16* __restrict__ x16,
                                             const _Float16* __restrict__ wt,
                                             const float* __restrict__ pos,
                                             _Float16* __restrict__ q16,
                                             _Float16* __restrict__ k16,
                                             _Float16* __restrict__ v16) {
  __shared__ union {
    struct { _Float16 xa[64][72]; _Float16 wb[192][72]; } s;
    float q[64][193];
  } u;
  const int h = blockIdx.x;
  const int row0 = blockIdx.y * 64;
  const int t = threadIdx.x;
  const int wv = t >> 6;
  const int l = t & 63;
  const int lr = l & 15, lg = l >> 4;

  f32x4 acc[4][3] = {};
  for (int kt = 0; kt < 4; ++kt) {
    const int k0 = kt * 64;
#pragma unroll
    for (int i = 0; i < 2; ++i) {
      int idx = t + i * 256;
      int r = idx >> 3, c8 = (idx & 7) * 8;
      *(half8*)&u.s.xa[r][c8] = *(const half8*)&x16[(size_t)(row0 + r) * 256 + k0 + c8];
    }
#pragma unroll
    for (int i = 0; i < 6; ++i) {
      int idx = t + i * 256;
      int wc = idx >> 3, c8 = (idx & 7) * 8;
      int col = (wc >> 6) * 512 + h * 64 + (wc & 63);
      *(half8*)&u.s.wb[wc][c8] = *(const half8*)&wt[(size_t)col * 256 + k0 + c8];
    }
    __syncthreads();
#pragma unroll
    for (int sp = 0; sp < 2; ++sp) {
      const int koff = sp * 32 + lg * 8;
      half8 af[4], bf[3];
#pragma unroll
      for (int r = 0; r < 4; ++r) af[r] = *(half8*)&u.s.xa[r * 16 + lr][koff];
#pragma unroll
      for (int c = 0; c < 3; ++c) bf[c] = *(half8*)&u.s.wb[wv * 48 + c * 16 + lr][koff];
#pragma unroll
      for (int r = 0; r < 4; ++r)
#pragma unroll
        for (int c = 0; c < 3; ++c)
          acc[r][c] = __builtin_amdgcn_mfma_f32_16x16x32_f16(af[r], bf[c], acc[r][c], 0, 0, 0);
    }
    __syncthreads();
  }
  // spill accumulators to LDS as fp32 tile [row][col], col: 0..63=q, 64..127=k, 128..191=v
#pragma unroll
  for (int r = 0; r < 4; ++r)
#pragma unroll
    for (int c = 0; c < 3; ++c)
#pragma unroll
      for (int j = 0; j < 4; ++j)
        u.q[r * 16 + lg * 4 + j][wv * 48 + c * 16 + lr] = acc[r][c][j];
  __syncthreads();

  // epilogue: wave0 -> k (norm+rotary), wave1 -> v (norm), wave2 -> q (rotary)
  const int role = t >> 6;
  const int r = t & 63;
  if (role < 3) {
    const int grow = row0 + r;
    const int c0 = (role == 0) ? 64 : (role == 1 ? 128 : 0);
    float mean = 0.0f, inv = 1.0f;
    if (role <= 1) {
      float m2 = 0.0f;
#pragma unroll
      for (int i = 0; i < 64; ++i) {
        float v = u.q[r][c0 + i];
        mean += v; m2 += v * v;
      }
      mean *= (1.0f / 64.0f);
      float var = m2 * (1.0f / 64.0f) - mean * mean;
      inv = rsqrtf(var + 1e-5f);
    }
    float tv[64];
#pragma unroll
    for (int i = 0; i < 64; ++i) tv[i] = (u.q[r][c0 + i] - mean) * inv;
    if (role != 1) {
      const float px = pos[(size_t)grow * 2 + 0] * 64.0f;
      const float py = pos[(size_t)grow * 2 + 1] * 64.0f;
#pragma unroll
      for (int i = 0; i < 16; ++i) {
        // inv_freq = 10000^(-i/16) = exp2(-i * log2(10000)/16)
        float invf = exp2f((float)i * -0.8304820237218405f);
        float sx, cx, sy, cy;
        __sincosf(px * invf, &sx, &cx);
        __sincosf(py * invf, &sy, &cy);
        float a0 = tv[i], a1 = tv[i + 16], a2 = tv[i + 32], a3 = tv[i + 48];
        tv[i]      = a0 * cx - a1 * sx;
        tv[i + 16] = a1 * cx + a0 * sx;
        tv[i + 32] = a2 * cy - a3 * sy;
        tv[i + 48] = a3 * cy + a2 * sy;
      }
    }
    _Float16* dst = (role == 0 ? k16 : (role == 1 ? v16 : q16)) + (size_t)grow * 512 + h * 64;
#pragma unroll
    for (int c8 = 0; c8 < 8; ++c8) {
      half8 o;
#pragma unroll
      for (int j = 0; j < 8; ++j) o[j] = (_Float16)tv[c8 * 8 + j];
      *(half8*)(dst + c8 * 8) = o;
    }
  }
}

// ---------------- K2: dots partials ----------------
// grid(16 kchunks, 32 bh), 256 threads. part[chunk][bh][64][64]
__global__ void __launch_bounds__(256) k_dots(const _Float16* __restrict__ k16,
                                              const _Float16* __restrict__ v16,
                                              float* __restrict__ part) {
  __shared__ float kt[64][68];
  __shared__ float vt[64][68];
  const int chunk = blockIdx.x, bh = blockIdx.y;
  const int b = bh >> 3, h = bh & 7;
  const int t = threadIdx.x;
  const int d0 = (t & 15) * 4, e0 = (t >> 4) * 4;
  float acc[4][4] = {};
  for (int st = 0; st < 8; ++st) {
    const int n0 = chunk * 512 + st * 64;
#pragma unroll
    for (int i = 0; i < 2; ++i) {
      int idx = t + i * 256;
      int r = idx >> 3, c8 = (idx & 7) * 8;
      size_t src = ((size_t)(b * NN + n0 + r)) * 512 + h * 64 + c8;
      half8 hk = *(const half8*)&k16[src];
      half8 hv = *(const half8*)&v16[src];
      float4 f0 = make_float4((float)hk[0], (float)hk[1], (float)hk[2], (float)hk[3]);
      float4 f1 = make_float4((float)hk[4], (float)hk[5], (float)hk[6], (float)hk[7]);
      float4 g0 = make_float4((float)hv[0], (float)hv[1], (float)hv[2], (float)hv[3]);
      float4 g1 = make_float4((float)hv[4], (float)hv[5], (float)hv[6], (float)hv[7]);
      *(float4*)&kt[r][c8] = f0; *(float4*)&kt[r][c8 + 4] = f1;
      *(float4*)&vt[r][c8] = g0; *(float4*)&vt[r][c8 + 4] = g1;
    }
    __syncthreads();
#pragma unroll 16
    for (int r = 0; r < 64; ++r) {
      float4 kk = *(float4*)&kt[r][d0];
      float4 vv = *(float4*)&vt[r][e0];
      float ka[4] = {kk.x, kk.y, kk.z, kk.w};
      float va[4] = {vv.x, vv.y, vv.z, vv.w};
#pragma unroll
      for (int i = 0; i < 4; ++i)
#pragma unroll
        for (int j = 0; j < 4; ++j) acc[i][j] += ka[i] * va[j];
    }
    __syncthreads();
  }
  float* dst = part + ((size_t)chunk * 32 + bh) * 4096;
#pragma unroll
  for (int i = 0; i < 4; ++i)
#pragma unroll
    for (int j = 0; j < 4; ++j) dst[(d0 + i) * 64 + e0 + j] = acc[i][j];
}

// reduce 16 chunks -> dots [32][64][64]
__global__ void __launch_bounds__(256) k_red(const float* __restrict__ part,
                                             float* __restrict__ dots) {
  int i = blockIdx.x * 256 + threadIdx.x;  // 0..131071
  float s = 0.f;
#pragma unroll
  for (int c = 0; c < 16; ++c) s += part[(size_t)c * 131072 + i];
  dots[i] = s;
}

// ---------------- K2b: Wd[b][j][i] = (1/N) * sum_e dots[b,h,d,e] * W_out[h*64+e][j] ----------------
// stored transposed as wdt[b][j=0..255][i=0..511] fp16; grid(4, 32), 256 threads
__global__ void __launch_bounds__(256) k_wd(const float* __restrict__ dots,
                                            const float* __restrict__ wout,
                                            _Float16* __restrict__ wdt) {
  const int b = blockIdx.x;
  const int idx = blockIdx.y * 256 + threadIdx.x;  // 0..8191
  const int j = idx >> 5;
  const int i0 = (idx & 31) * 16;
  const int h = i0 >> 6, d0 = i0 & 63;
  const float* dp = dots + (size_t)(b * 8 + h) * 4096;
  float acc[16] = {};
  for (int e = 0; e < 64; ++e) {
    float w = wout[(size_t)(h * 64 + e) * 256 + j];
#pragma unroll
    for (int ii = 0; ii < 16; ++ii) acc[ii] += dp[(d0 + ii) * 64 + e] * w;
  }
  const float scale = 1.0f / 8192.0f;
  _Float16* dst = wdt + (size_t)b * 131072 + (size_t)j * 512 + i0;
#pragma unroll
  for (int c8 = 0; c8 < 2; ++c8) {
    half8 o;
#pragma unroll
    for (int q = 0; q < 8; ++q) o[q] = (_Float16)(acc[c8 * 8 + q] * scale);
    *(half8*)(dst + c8 * 8) = o;
  }
}

// ---------------- K3: out = q16 @ Wd[b] + b_out ----------------
// grid(512 rowtiles), 256 threads. Tile 64 rows x 256 cols, K=512.
__global__ void __launch_bounds__(256) k_out(const _Float16* __restrict__ q16,
                                             const _Float16* __restrict__ wdt,
                                             const float* __restrict__ bout,
                                             float* __restrict__ out) {
  __shared__ struct { _Float16 qa[64][72]; _Float16 wt[256][72]; } s;
  const int row0 = blockIdx.x * 64;
  const int b = row0 >> 13;
  const _Float16* wb = wdt + (size_t)b * 131072;
  const int t = threadIdx.x;
  const int wv = t >> 6, l = t & 63;
  const int lr = l & 15, lg = l >> 4;
  f32x4 acc[4][4] = {};
  for (int kt = 0; kt < 8; ++kt) {
    const int k0 = kt * 64;
#pragma unroll
    for (int i = 0; i < 2; ++i) {
      int idx = t + i * 256;
      int r = idx >> 3, c8 = (idx & 7) * 8;
      *(half8*)&s.qa[r][c8] = *(const half8*)&q16[(size_t)(row0 + r) * 512 + k0 + c8];
    }
#pragma unroll
    for (int i = 0; i < 8; ++i) {
      int idx = t + i * 256;
      int j = idx >> 3, c8 = (idx & 7) * 8;
      *(half8*)&s.wt[j][c8] = *(const half8*)&wb[(size_t)j * 512 + k0 + c8];
    }
    __syncthreads();
#pragma unroll
    for (int sp = 0; sp < 2; ++sp) {
      const int koff = sp * 32 + lg * 8;
      half8 af[4], bf[4];
#pragma unroll
      for (int r = 0; r < 4; ++r) af[r] = *(half8*)&s.qa[r * 16 + lr][koff];
#pragma unroll
      for (int c = 0; c < 4; ++c) bf[c] = *(half8*)&s.wt[wv * 64 + c * 16 + lr][koff];
#pragma unroll
      for (int r = 0; r < 4; ++r)
#pragma unroll
        for (int c = 0; c < 4; ++c)
          acc[r][c] = __builtin_amdgcn_mfma_f32_16x16x32_f16(af[r], bf[c], acc[r][c], 0, 0, 0);
    }
    __syncthreads();
  }
#pragma unroll
  for (int r = 0; r < 4; ++r)
#pragma unroll
    for (int c = 0; c < 4; ++c) {
      int col = wv * 64 + c * 16 + lr;
      float bo = bout[col];
#pragma unroll
      for (int j = 0; j < 4; ++j) {
        int grow = row0 + r * 16 + lg * 4 + j;
        out[(size_t)grow * 256 + col] = acc[r][c][j] + bo;
      }
    }
}

// ---------------- launch ----------------
extern "C" void kernel_launch(void* const* d_in, const int* in_sizes, int n_in,
                              void* d_out, int out_size, void* d_ws, size_t ws_size,
                              hipStream_t stream) {
  const float* x    = (const float*)d_in[0];
  const float* pos  = (const float*)d_in[1];
  const float* wqkv = (const float*)d_in[2];
  const float* wout = (const float*)d_in[3];
  const float* bout = (const float*)d_in[4];
  float* out = (float*)d_out;
  char* ws = (char*)d_ws;

  _Float16* x16  = (_Float16*)(ws + 0);           // 16,777,216 B
  _Float16* wt16 = (_Float16*)(ws + 16777216);    //    786,432 B
  _Float16* q16  = (_Float16*)(ws + 17563648);    // 33,554,432 B
  _Float16* k16  = (_Float16*)(ws + 51118080);    // 33,554,432 B
  _Float16* v16  = (_Float16*)(ws + 84672512);    // 33,554,432 B
  float*    part = (float*)   (ws + 118226944);   //  8,388,608 B
  float*    dots = (float*)   (ws + 126615552);   //    524,288 B
  _Float16* wdt  = (_Float16*)(ws + 127139840);   //  1,048,576 B  (end 128,188,416)

  k_cvt_x<<<4096, 256, 0, stream>>>(x, x16);
  k_cvt_w<<<1536, 256, 0, stream>>>(wqkv, wt16);
  k_qkv<<<dim3(8, 512), 256, 0, stream>>>(x16, wt16, pos, q16, k16, v16);
  k_dots<<<dim3(16, 32), 256, 0, stream>>>(k16, v16, part);
  k_red<<<512, 256, 0, stream>>>(part, dots);
  k_wd<<<dim3(4, 32), 256, 0, stream>>>(dots, wout, wdt);
  k_out<<<512, 256, 0, stream>>>(q16, wdt, bout, out);
}

// Round 2
// 189.278 us; speedup vs baseline: 1.2403x; 1.2403x over previous
//
#include <hip/hip_runtime.h>
#include <hip/hip_fp16.h>

#define BB 4
#define NN 8192
#define DD 256
#define HH 8
#define MM 32768   // BB*NN

typedef __attribute__((ext_vector_type(8))) _Float16 half8;
typedef __attribute__((ext_vector_type(4))) float f32x4;

#define GLL(src, dst)                                                        \
  __builtin_amdgcn_global_load_lds(                                          \
      (const __attribute__((address_space(1))) void*)(src),                  \
      (__attribute__((address_space(3))) void*)(dst), 16, 0, 0)

// ---------------- K0: W conversion ----------------
// W_qkv [256][1536] fp32 -> Wt [1536][256] fp16 (transposed)
__global__ void __launch_bounds__(256) k_cvt_w(const float* __restrict__ w,
                                               _Float16* __restrict__ wt) {
  int idx = blockIdx.x * 256 + threadIdx.x;  // 0..393215
  int k = idx / 1536, c = idx % 1536;
  wt[(size_t)c * 256 + k] = (_Float16)w[idx];
}

// ---------------- K1: qkv GEMM (all heads per block) + norm + rotary ----------------
// grid(512): 64 rows x 1536 cols, K=256. 4 waves, wave wv owns rows wv*16..+15.
// Per head h: 12 col-frags (q:0-3, k:4-7, v:8-11). Epilogue is register-only.
__global__ void __launch_bounds__(256) k_qkv(const float* __restrict__ x,
                                             const _Float16* __restrict__ wt,
                                             const float* __restrict__ pos,
                                             _Float16* __restrict__ q16,
                                             _Float16* __restrict__ k16,
                                             _Float16* __restrict__ v16) {
  __shared__ alignas(16) _Float16 xa[16384];      // [64 rows][256 K] swizzled, 32 KB
  __shared__ alignas(16) _Float16 wb[2][12288];   // [192 cols][64 K] swizzled, 24 KB x2
  const int row0 = blockIdx.x * 64;
  const int t = threadIdx.x;
  const int wv = t >> 6, l = t & 63, lr = l & 15, lg = l >> 4;

  // ---- stage x: fp32 -> fp16 into swizzled LDS (once per block) ----
#pragma unroll
  for (int it = 0; it < 8; ++it) {
    int o = it * 4096 + t * 16;                    // physical byte offset
    int row = o >> 9;
    int colb = (o & 511) ^ ((row & 7) << 4);       // logical col byte (XOR involution)
    const float* src = x + (size_t)(row0 + row) * 256 + (colb >> 1);
    float4 a = *(const float4*)src;
    float4 b = *(const float4*)(src + 4);
    half8 hv;
    hv[0] = (_Float16)a.x; hv[1] = (_Float16)a.y; hv[2] = (_Float16)a.z; hv[3] = (_Float16)a.w;
    hv[4] = (_Float16)b.x; hv[5] = (_Float16)b.y; hv[6] = (_Float16)b.z; hv[7] = (_Float16)b.w;
    *(half8*)((char*)xa + o) = hv;
  }

  // ---- hoist rotary angles: same for every head ----
  const float invf = exp2f((float)lr * -0.8304820237218405f);  // 10000^(-lr/16)
  float sx[4], cx[4], sy[4], cy[4];
#pragma unroll
  for (int j = 0; j < 4; ++j) {
    int grow = row0 + wv * 16 + lg * 4 + j;
    float px = pos[(size_t)grow * 2 + 0] * 64.0f * invf;
    float py = pos[(size_t)grow * 2 + 1] * 64.0f * invf;
    __sincosf(px, &sx[j], &cx[j]);
    __sincosf(py, &sy[j], &cy[j]);
  }

  // ---- W staging: global_load_lds, pre-swizzled source ----
  auto stageW = [&](int buf, int hh, int kt) {
#pragma unroll
    for (int call = 0; call < 6; ++call) {
      int ob = (call * 4 + wv) * 1024;             // wave-uniform dest base (bytes)
      int o = ob + l * 16;                         // this lane's dest byte
      int c = o >> 7;                              // col 0..191
      int kb = (o & 127) ^ ((c & 7) << 4);         // logical K byte
      int gc = ((c >> 6) << 9) + (hh << 6) + (c & 63);  // global wt row
      const char* src = (const char*)(wt + (size_t)gc * 256 + kt * 64) + kb;
      GLL(src, (char*)&wb[buf][0] + ob);
    }
  };

  stageW(0, 0, 0);
  __syncthreads();

  int cur = 0;
#pragma unroll 1
  for (int h = 0; h < 8; ++h) {
    f32x4 acc[12] = {};
#pragma unroll 1
    for (int kt = 0; kt < 4; ++kt) {
      int ni = (h << 2) + kt + 1;
      if (ni < 32) stageW(cur ^ 1, ni >> 2, ni & 3);
      const int arow = wv * 16 + lr;
      const char* wbp = (const char*)&wb[cur][0];
#pragma unroll
      for (int sp = 0; sp < 2; ++sp) {
        int kbl = kt * 128 + sp * 64 + lg * 16;
        half8 af = *(const half8*)((const char*)xa + arow * 512 + (kbl ^ ((arow & 7) << 4)));
        int wkb = sp * 64 + lg * 16;
#pragma unroll
        for (int cf = 0; cf < 12; ++cf) {
          int c = cf * 16 + lr;
          half8 bf = *(const half8*)(wbp + c * 128 + (wkb ^ ((c & 7) << 4)));
          acc[cf] = __builtin_amdgcn_mfma_f32_16x16x32_f16(af, bf, acc[cf], 0, 0, 0);
        }
      }
      __syncthreads();
      cur ^= 1;
    }
    // ---- epilogue (register-only): norm k,v; rotary q,k; store ----
#pragma unroll
    for (int j = 0; j < 4; ++j) {
      float k0 = acc[4][j], k1 = acc[5][j], k2 = acc[6][j], k3 = acc[7][j];
      float v0 = acc[8][j], v1 = acc[9][j], v2 = acc[10][j], v3 = acc[11][j];
      float sk = k0 + k1 + k2 + k3, sk2 = k0 * k0 + k1 * k1 + k2 * k2 + k3 * k3;
      float sv = v0 + v1 + v2 + v3, sv2 = v0 * v0 + v1 * v1 + v2 * v2 + v3 * v3;
#pragma unroll
      for (int m = 1; m < 16; m <<= 1) {
        sk += __shfl_xor(sk, m, 64);  sk2 += __shfl_xor(sk2, m, 64);
        sv += __shfl_xor(sv, m, 64);  sv2 += __shfl_xor(sv2, m, 64);
      }
      float mk = sk * 0.015625f, mv = sv * 0.015625f;
      float ik = rsqrtf(sk2 * 0.015625f - mk * mk + 1e-5f);
      float iv = rsqrtf(sv2 * 0.015625f - mv * mv + 1e-5f);
      k0 = (k0 - mk) * ik; k1 = (k1 - mk) * ik; k2 = (k2 - mk) * ik; k3 = (k3 - mk) * ik;
      v0 = (v0 - mv) * iv; v1 = (v1 - mv) * iv; v2 = (v2 - mv) * iv; v3 = (v3 - mv) * iv;
      float q0 = acc[0][j], q1 = acc[1][j], q2 = acc[2][j], q3 = acc[3][j];
      float rq0 = q0 * cx[j] - q1 * sx[j], rq1 = q1 * cx[j] + q0 * sx[j];
      float rq2 = q2 * cy[j] - q3 * sy[j], rq3 = q3 * cy[j] + q2 * sy[j];
      float rk0 = k0 * cx[j] - k1 * sx[j], rk1 = k1 * cx[j] + k0 * sx[j];
      float rk2 = k2 * cy[j] - k3 * sy[j], rk3 = k3 * cy[j] + k2 * sy[j];
      size_t base = (size_t)(row0 + wv * 16 + lg * 4 + j) * 512 + h * 64 + lr;
      q16[base] = (_Float16)rq0; q16[base + 16] = (_Float16)rq1;
      q16[base + 32] = (_Float16)rq2; q16[base + 48] = (_Float16)rq3;
      k16[base] = (_Float16)rk0; k16[base + 16] = (_Float16)rk1;
      k16[base + 32] = (_Float16)rk2; k16[base + 48] = (_Float16)rk3;
      v16[base] = (_Float16)v0;  v16[base + 16] = (_Float16)v1;
      v16[base + 32] = (_Float16)v2;  v16[base + 48] = (_Float16)v3;
    }
  }
}

// ---------------- K2: dots partials ----------------
__global__ void __launch_bounds__(256) k_dots(const _Float16* __restrict__ k16,
                                              const _Float16* __restrict__ v16,
                                              float* __restrict__ part) {
  __shared__ float kt[64][68];
  __shared__ float vt[64][68];
  const int chunk = blockIdx.x, bh = blockIdx.y;
  const int b = bh >> 3, h = bh & 7;
  const int t = threadIdx.x;
  const int d0 = (t & 15) * 4, e0 = (t >> 4) * 4;
  float acc[4][4] = {};
  for (int st = 0; st < 8; ++st) {
    const int n0 = chunk * 512 + st * 64;
#pragma unroll
    for (int i = 0; i < 2; ++i) {
      int idx = t + i * 256;
      int r = idx >> 3, c8 = (idx & 7) * 8;
      size_t src = ((size_t)(b * NN + n0 + r)) * 512 + h * 64 + c8;
      half8 hk = *(const half8*)&k16[src];
      half8 hv = *(const half8*)&v16[src];
      float4 f0 = make_float4((float)hk[0], (float)hk[1], (float)hk[2], (float)hk[3]);
      float4 f1 = make_float4((float)hk[4], (float)hk[5], (float)hk[6], (float)hk[7]);
      float4 g0 = make_float4((float)hv[0], (float)hv[1], (float)hv[2], (float)hv[3]);
      float4 g1 = make_float4((float)hv[4], (float)hv[5], (float)hv[6], (float)hv[7]);
      *(float4*)&kt[r][c8] = f0; *(float4*)&kt[r][c8 + 4] = f1;
      *(float4*)&vt[r][c8] = g0; *(float4*)&vt[r][c8 + 4] = g1;
    }
    __syncthreads();
#pragma unroll 16
    for (int r = 0; r < 64; ++r) {
      float4 kk = *(float4*)&kt[r][d0];
      float4 vv = *(float4*)&vt[r][e0];
      float ka[4] = {kk.x, kk.y, kk.z, kk.w};
      float va[4] = {vv.x, vv.y, vv.z, vv.w};
#pragma unroll
      for (int i = 0; i < 4; ++i)
#pragma unroll
        for (int j = 0; j < 4; ++j) acc[i][j] += ka[i] * va[j];
    }
    __syncthreads();
  }
  float* dst = part + ((size_t)chunk * 32 + bh) * 4096;
#pragma unroll
  for (int i = 0; i < 4; ++i)
#pragma unroll
    for (int j = 0; j < 4; ++j) dst[(d0 + i) * 64 + e0 + j] = acc[i][j];
}

// reduce 16 chunks -> dots [32][64][64]
__global__ void __launch_bounds__(256) k_red(const float* __restrict__ part,
                                             float* __restrict__ dots) {
  int i = blockIdx.x * 256 + threadIdx.x;  // 0..131071
  float s = 0.f;
#pragma unroll
  for (int c = 0; c < 16; ++c) s += part[(size_t)c * 131072 + i];
  dots[i] = s;
}

// ---------------- K2b: wdt[b][j][i] = (1/N) * sum_e dots[b,h,d,e] * W_out[h*64+e][j]
__global__ void __launch_bounds__(256) k_wd(const float* __restrict__ dots,
                                            const float* __restrict__ wout,
                                            _Float16* __restrict__ wdt) {
  const int b = blockIdx.x;
  const int idx = blockIdx.y * 256 + threadIdx.x;  // 0..8191
  const int j = idx >> 5;
  const int i0 = (idx & 31) * 16;
  const int h = i0 >> 6, d0 = i0 & 63;
  const float* dp = dots + (size_t)(b * 8 + h) * 4096;
  float acc[16] = {};
  for (int e = 0; e < 64; ++e) {
    float w = wout[(size_t)(h * 64 + e) * 256 + j];
#pragma unroll
    for (int ii = 0; ii < 16; ++ii) acc[ii] += dp[(d0 + ii) * 64 + e] * w;
  }
  const float scale = 1.0f / 8192.0f;
  _Float16* dst = wdt + (size_t)b * 131072 + (size_t)j * 512 + i0;
#pragma unroll
  for (int c8 = 0; c8 < 2; ++c8) {
    half8 o;
#pragma unroll
    for (int q = 0; q < 8; ++q) o[q] = (_Float16)(acc[c8 * 8 + q] * scale);
    *(half8*)(dst + c8 * 8) = o;
  }
}

// ---------------- K3: out = q16 @ wdt[b] + b_out ----------------
// grid(512): 64 rows x 256 cols, K=512. gll-staged, swizzled, double-buffered.
__global__ void __launch_bounds__(256) k_out(const _Float16* __restrict__ q16,
                                             const _Float16* __restrict__ wdt,
                                             const float* __restrict__ bout,
                                             float* __restrict__ out) {
  __shared__ alignas(16) _Float16 qa[2][4096];     // [64 rows][64 K] 8 KB x2
  __shared__ alignas(16) _Float16 wtile[2][16384]; // [256 cols][64 K] 32 KB x2
  const int row0 = blockIdx.x * 64;
  const int b = row0 >> 13;
  const _Float16* wb = wdt + (size_t)b * 131072;
  const int t = threadIdx.x, wv = t >> 6, l = t & 63, lr = l & 15, lg = l >> 4;

  auto stage = [&](int buf, int kt) {
#pragma unroll
    for (int call = 0; call < 2; ++call) {
      int ob = (call * 4 + wv) * 1024;
      int o = ob + l * 16;
      int r = o >> 7;
      int kb = (o & 127) ^ ((r & 7) << 4);
      const char* src = (const char*)(q16 + (size_t)(row0 + r) * 512 + kt * 64) + kb;
      GLL(src, (char*)&qa[buf][0] + ob);
    }
#pragma unroll
    for (int call = 0; call < 8; ++call) {
      int ob = (call * 4 + wv) * 1024;
      int o = ob + l * 16;
      int c = o >> 7;
      int kb = (o & 127) ^ ((c & 7) << 4);
      const char* src = (const char*)(wb + (size_t)c * 512 + kt * 64) + kb;
      GLL(src, (char*)&wtile[buf][0] + ob);
    }
  };

  f32x4 acc[16] = {};
  stage(0, 0);
  __syncthreads();
#pragma unroll 1
  for (int kt = 0; kt < 8; ++kt) {
    int cur = kt & 1;
    if (kt < 7) stage(cur ^ 1, kt + 1);
    const int arow = wv * 16 + lr;
#pragma unroll
    for (int sp = 0; sp < 2; ++sp) {
      int kb = sp * 64 + lg * 16;
      half8 af = *(const half8*)((const char*)&qa[cur][0] + arow * 128 + (kb ^ ((arow & 7) << 4)));
#pragma unroll
      for (int cf = 0; cf < 16; ++cf) {
        int c = cf * 16 + lr;
        half8 bf = *(const half8*)((const char*)&wtile[cur][0] + c * 128 + (kb ^ ((c & 7) << 4)));
        acc[cf] = __builtin_amdgcn_mfma_f32_16x16x32_f16(af, bf, acc[cf], 0, 0, 0);
      }
    }
    __syncthreads();
  }
#pragma unroll
  for (int cf = 0; cf < 16; ++cf) {
    int col = cf * 16 + lr;
    float bo = bout[col];
#pragma unroll
    for (int j = 0; j < 4; ++j) {
      int grow = row0 + wv * 16 + lg * 4 + j;
      out[(size_t)grow * 256 + col] = acc[cf][j] + bo;
    }
  }
}

// ---------------- launch ----------------
extern "C" void kernel_launch(void* const* d_in, const int* in_sizes, int n_in,
                              void* d_out, int out_size, void* d_ws, size_t ws_size,
                              hipStream_t stream) {
  const float* x    = (const float*)d_in[0];
  const float* pos  = (const float*)d_in[1];
  const float* wqkv = (const float*)d_in[2];
  const float* wout = (const float*)d_in[3];
  const float* bout = (const float*)d_in[4];
  float* out = (float*)d_out;
  char* ws = (char*)d_ws;

  _Float16* wt16 = (_Float16*)(ws + 0);           //    786,432 B
  _Float16* q16  = (_Float16*)(ws + 786432);      // 33,554,432 B
  _Float16* k16  = (_Float16*)(ws + 34340864);    // 33,554,432 B
  _Float16* v16  = (_Float16*)(ws + 67895296);    // 33,554,432 B
  float*    part = (float*)   (ws + 101449728);   //  8,388,608 B
  float*    dots = (float*)   (ws + 109838336);   //    524,288 B
  _Float16* wdt  = (_Float16*)(ws + 110362624);   //  1,048,576 B (end 111,411,200)

  k_cvt_w<<<1536, 256, 0, stream>>>(wqkv, wt16);
  k_qkv<<<512, 256, 0, stream>>>(x, wt16, pos, q16, k16, v16);
  k_dots<<<dim3(16, 32), 256, 0, stream>>>(k16, v16, part);
  k_red<<<512, 256, 0, stream>>>(part, dots);
  k_wd<<<dim3(4, 32), 256, 0, stream>>>(dots, wout, wdt);
  k_out<<<512, 256, 0, stream>>>(q16, wdt, bout, out);
}

// Round 3
// 149.666 us; speedup vs baseline: 1.5686x; 1.2647x over previous
//
#include <hip/hip_runtime.h>
#include <hip/hip_fp16.h>

#define BB 4
#define NN 8192
#define DD 256
#define HH 8
#define MM 32768   // BB*NN

typedef __attribute__((ext_vector_type(8))) _Float16 half8;
typedef __attribute__((ext_vector_type(4))) _Float16 half4;
typedef __attribute__((ext_vector_type(4))) float f32x4;

#define GLL(src, dst)                                                        \
  __builtin_amdgcn_global_load_lds(                                          \
      (const __attribute__((address_space(1))) void*)(src),                  \
      (__attribute__((address_space(3))) void*)(dst), 16, 0, 0)

// ---------------- K0: W conversion ----------------
// W_qkv [256][1536] fp32 -> Wt [1536][256] fp16 (transposed)
__global__ void __launch_bounds__(256) k_cvt_w(const float* __restrict__ w,
                                               _Float16* __restrict__ wt) {
  int idx = blockIdx.x * 256 + threadIdx.x;  // 0..393215
  int k = idx / 1536, c = idx % 1536;
  wt[(size_t)c * 256 + k] = (_Float16)w[idx];
}

// ---------------- K1: qkv GEMM (all heads per block) + norm + rotary ----------------
// grid(512): 64 rows x 1536 cols, K=256. 4 waves; wave wv owns x-rows wv*16..+15.
// MFMA with A=W-frag, B=x-frag: lane (lr,lg) holds cols lg*4+{0..3} of row lr.
__global__ void __launch_bounds__(256) k_qkv(const float* __restrict__ x,
                                             const _Float16* __restrict__ wt,
                                             const float* __restrict__ pos,
                                             _Float16* __restrict__ q16,
                                             _Float16* __restrict__ k16,
                                             _Float16* __restrict__ v16) {
  __shared__ alignas(16) _Float16 xa[16384];      // [64 rows][256 K] swizzled, 32 KB
  __shared__ alignas(16) _Float16 wb[2][12288];   // [192 cols][64 K] swizzled, 24 KB x2
  const int row0 = blockIdx.x * 64;
  const int t = threadIdx.x;
  const int wv = t >> 6, l = t & 63, lr = l & 15, lg = l >> 4;

  // ---- stage x: fp32 -> fp16 into swizzled LDS (once per block) ----
#pragma unroll
  for (int it = 0; it < 8; ++it) {
    int o = it * 4096 + t * 16;                    // physical byte offset
    int row = o >> 9;
    int colb = (o & 511) ^ ((row & 7) << 4);       // logical col byte (XOR involution)
    const float* src = x + (size_t)(row0 + row) * 256 + (colb >> 1);
    float4 a = *(const float4*)src;
    float4 b = *(const float4*)(src + 4);
    half8 hv;
    hv[0] = (_Float16)a.x; hv[1] = (_Float16)a.y; hv[2] = (_Float16)a.z; hv[3] = (_Float16)a.w;
    hv[4] = (_Float16)b.x; hv[5] = (_Float16)b.y; hv[6] = (_Float16)b.z; hv[7] = (_Float16)b.w;
    *(half8*)((char*)xa + o) = hv;
  }

  // ---- hoist rotary angles: freq index = lg*4+j, row = wv*16+lr ----
  const int myrow = row0 + wv * 16 + lr;
  const float px = pos[(size_t)myrow * 2 + 0] * 64.0f;
  const float py = pos[(size_t)myrow * 2 + 1] * 64.0f;
  float sxj[4], cxj[4], syj[4], cyj[4];
#pragma unroll
  for (int j = 0; j < 4; ++j) {
    float invf = exp2f((float)(lg * 4 + j) * -0.8304820237218405f);  // 10000^(-fi/16)
    __sincosf(px * invf, &sxj[j], &cxj[j]);
    __sincosf(py * invf, &syj[j], &cyj[j]);
  }

  // ---- W staging: global_load_lds, pre-swizzled source ----
  auto stageW = [&](int buf, int hh, int kt) {
#pragma unroll
    for (int call = 0; call < 6; ++call) {
      int ob = (call * 4 + wv) * 1024;             // wave-uniform dest base (bytes)
      int o = ob + l * 16;                         // this lane's dest byte
      int c = o >> 7;                              // col 0..191
      int kb = (o & 127) ^ ((c & 7) << 4);         // logical K byte
      int gc = ((c >> 6) << 9) + (hh << 6) + (c & 63);  // global wt row
      const char* src = (const char*)(wt + (size_t)gc * 256 + kt * 64) + kb;
      GLL(src, (char*)&wb[buf][0] + ob);
    }
  };

  stageW(0, 0, 0);
  __syncthreads();

  int cur = 0;
#pragma unroll 1
  for (int h = 0; h < 8; ++h) {
    f32x4 acc[12] = {};
#pragma unroll 1
    for (int kt = 0; kt < 4; ++kt) {
      int ni = (h << 2) + kt + 1;
      if (ni < 32) stageW(cur ^ 1, ni >> 2, ni & 3);
      const int arow = wv * 16 + lr;
      const char* wbp = (const char*)&wb[cur][0];
#pragma unroll
      for (int sp = 0; sp < 2; ++sp) {
        int kbl = kt * 128 + sp * 64 + lg * 16;
        half8 af = *(const half8*)((const char*)xa + arow * 512 + (kbl ^ ((arow & 7) << 4)));
        int wkb = sp * 64 + lg * 16;
#pragma unroll
        for (int cf = 0; cf < 12; ++cf) {
          int c = cf * 16 + lr;
          half8 bf = *(const half8*)(wbp + c * 128 + (wkb ^ ((c & 7) << 4)));
          // SWAPPED: A = W fragment, B = x fragment -> D[wcol][xrow]
          acc[cf] = __builtin_amdgcn_mfma_f32_16x16x32_f16(bf, af, acc[cf], 0, 0, 0);
        }
      }
      __syncthreads();
      cur ^= 1;
    }
    // ---- epilogue (register-only): lane holds cols lg*4+{0..3} of row lr ----
    float sk = 0.f, sk2 = 0.f, sv = 0.f, sv2 = 0.f;
#pragma unroll
    for (int cc = 4; cc < 12; ++cc)
#pragma unroll
      for (int j = 0; j < 4; ++j) {
        float u = acc[cc][j];
        if (cc < 8) { sk += u; sk2 += u * u; } else { sv += u; sv2 += u * u; }
      }
    sk += __shfl_xor(sk, 16, 64);  sk += __shfl_xor(sk, 32, 64);
    sk2 += __shfl_xor(sk2, 16, 64); sk2 += __shfl_xor(sk2, 32, 64);
    sv += __shfl_xor(sv, 16, 64);  sv += __shfl_xor(sv, 32, 64);
    sv2 += __shfl_xor(sv2, 16, 64); sv2 += __shfl_xor(sv2, 32, 64);
    float mk = sk * 0.015625f, mv = sv * 0.015625f;
    float ik = rsqrtf(sk2 * 0.015625f - mk * mk + 1e-5f);
    float iv = rsqrtf(sv2 * 0.015625f - mv * mv + 1e-5f);

    half4 oq[4], ok[4], ov[4];
#pragma unroll
    for (int j = 0; j < 4; ++j) {
      float q0 = acc[0][j], q1 = acc[1][j], q2 = acc[2][j], q3 = acc[3][j];
      oq[0][j] = (_Float16)(q0 * cxj[j] - q1 * sxj[j]);
      oq[1][j] = (_Float16)(q1 * cxj[j] + q0 * sxj[j]);
      oq[2][j] = (_Float16)(q2 * cyj[j] - q3 * syj[j]);
      oq[3][j] = (_Float16)(q3 * cyj[j] + q2 * syj[j]);
      float k0 = (acc[4][j] - mk) * ik, k1 = (acc[5][j] - mk) * ik;
      float k2 = (acc[6][j] - mk) * ik, k3 = (acc[7][j] - mk) * ik;
      ok[0][j] = (_Float16)(k0 * cxj[j] - k1 * sxj[j]);
      ok[1][j] = (_Float16)(k1 * cxj[j] + k0 * sxj[j]);
      ok[2][j] = (_Float16)(k2 * cyj[j] - k3 * syj[j]);
      ok[3][j] = (_Float16)(k3 * cyj[j] + k2 * syj[j]);
      ov[0][j] = (_Float16)((acc[8][j]  - mv) * iv);
      ov[1][j] = (_Float16)((acc[9][j]  - mv) * iv);
      ov[2][j] = (_Float16)((acc[10][j] - mv) * iv);
      ov[3][j] = (_Float16)((acc[11][j] - mv) * iv);
    }
    size_t base = (size_t)myrow * 512 + h * 64 + lg * 4;
#pragma unroll
    for (int cc = 0; cc < 4; ++cc) {
      *(half4*)(q16 + base + cc * 16) = oq[cc];
      *(half4*)(k16 + base + cc * 16) = ok[cc];
      *(half4*)(v16 + base + cc * 16) = ov[cc];
    }
  }
}

// ---------------- K2: dots partials ----------------
__global__ void __launch_bounds__(256) k_dots(const _Float16* __restrict__ k16,
                                              const _Float16* __restrict__ v16,
                                              float* __restrict__ part) {
  __shared__ float kt[64][68];
  __shared__ float vt[64][68];
  const int chunk = blockIdx.x, bh = blockIdx.y;
  const int b = bh >> 3, h = bh & 7;
  const int t = threadIdx.x;
  const int d0 = (t & 15) * 4, e0 = (t >> 4) * 4;
  float acc[4][4] = {};
  for (int st = 0; st < 8; ++st) {
    const int n0 = chunk * 512 + st * 64;
#pragma unroll
    for (int i = 0; i < 2; ++i) {
      int idx = t + i * 256;
      int r = idx >> 3, c8 = (idx & 7) * 8;
      size_t src = ((size_t)(b * NN + n0 + r)) * 512 + h * 64 + c8;
      half8 hk = *(const half8*)&k16[src];
      half8 hv = *(const half8*)&v16[src];
      float4 f0 = make_float4((float)hk[0], (float)hk[1], (float)hk[2], (float)hk[3]);
      float4 f1 = make_float4((float)hk[4], (float)hk[5], (float)hk[6], (float)hk[7]);
      float4 g0 = make_float4((float)hv[0], (float)hv[1], (float)hv[2], (float)hv[3]);
      float4 g1 = make_float4((float)hv[4], (float)hv[5], (float)hv[6], (float)hv[7]);
      *(float4*)&kt[r][c8] = f0; *(float4*)&kt[r][c8 + 4] = f1;
      *(float4*)&vt[r][c8] = g0; *(float4*)&vt[r][c8 + 4] = g1;
    }
    __syncthreads();
#pragma unroll 16
    for (int r = 0; r < 64; ++r) {
      float4 kk = *(float4*)&kt[r][d0];
      float4 vv = *(float4*)&vt[r][e0];
      float ka[4] = {kk.x, kk.y, kk.z, kk.w};
      float va[4] = {vv.x, vv.y, vv.z, vv.w};
#pragma unroll
      for (int i = 0; i < 4; ++i)
#pragma unroll
        for (int j = 0; j < 4; ++j) acc[i][j] += ka[i] * va[j];
    }
    __syncthreads();
  }
  float* dst = part + ((size_t)chunk * 32 + bh) * 4096;
#pragma unroll
  for (int i = 0; i < 4; ++i)
#pragma unroll
    for (int j = 0; j < 4; ++j) dst[(d0 + i) * 64 + e0 + j] = acc[i][j];
}

// ---------------- K2b (fused red + wd, MFMA) ----------------
// grid(32): bid = b*8+h. wdt[b][j][h*64+d] = (1/N) sum_e dots[b,h,d,e] wout[h*64+e][j]
__global__ void __launch_bounds__(256) k_wd(const float* __restrict__ part,
                                            const float* __restrict__ wout,
                                            _Float16* __restrict__ wdt) {
  __shared__ alignas(16) _Float16 a_lds[4096];    // [64 d][64 e] swizzled, 8 KB
  __shared__ alignas(16) _Float16 b_lds[16384];   // [256 j][64 e] swizzled, 32 KB
  const int bid = blockIdx.x, b = bid >> 3, hh = bid & 7;
  const int t = threadIdx.x, wv = t >> 6, l = t & 63, lr = l & 15, lg = l >> 4;

  // A: reduce 16 chunks of part[chunk][bid][4096], scale by 1/8192, cvt fp16
#pragma unroll
  for (int g = 0; g < 4; ++g) {
    int i4 = (g * 256 + t) * 4;  // 0..4095
    f32x4 s = {};
#pragma unroll
    for (int c = 0; c < 16; ++c)
      s += *(const f32x4*)(part + ((size_t)c * 32 + bid) * 4096 + i4);
    int d = i4 >> 6, e2 = (i4 & 63) * 2;
    half4 o;
#pragma unroll
    for (int m = 0; m < 4; ++m) o[m] = (_Float16)(s[m] * (1.0f / 8192.0f));
    *(half4*)((char*)a_lds + d * 128 + (e2 ^ ((d & 7) << 4))) = o;
  }
  // B: wout rows hh*64..+63, transposed to [j][e] fp16
#pragma unroll
  for (int g = 0; g < 16; ++g) {
    int i4 = (g * 256 + t) * 4;  // 0..16383
    int e = i4 >> 8, j0 = i4 & 255;
    f32x4 u = *(const f32x4*)(wout + (size_t)(hh * 64 + e) * 256 + j0);
#pragma unroll
    for (int m = 0; m < 4; ++m) {
      int j = j0 + m;
      *(_Float16*)((char*)b_lds + j * 128 + ((e * 2) ^ ((j & 7) << 4))) = (_Float16)u[m];
    }
  }
  __syncthreads();

  f32x4 acc[4][4] = {};
#pragma unroll
  for (int sp = 0; sp < 2; ++sp) {
    int kb = sp * 64 + lg * 16;
    half8 af[4], bf[4];
#pragma unroll
    for (int ad = 0; ad < 4; ++ad) {
      int d = ad * 16 + lr;
      af[ad] = *(const half8*)((const char*)a_lds + d * 128 + (kb ^ ((d & 7) << 4)));
    }
#pragma unroll
    for (int bj = 0; bj < 4; ++bj) {
      int j = wv * 64 + bj * 16 + lr;
      bf[bj] = *(const half8*)((const char*)b_lds + j * 128 + (kb ^ ((j & 7) << 4)));
    }
#pragma unroll
    for (int ad = 0; ad < 4; ++ad)
#pragma unroll
      for (int bj = 0; bj < 4; ++bj)
        acc[ad][bj] = __builtin_amdgcn_mfma_f32_16x16x32_f16(af[ad], bf[bj], acc[ad][bj], 0, 0, 0);
  }
  // D[row=d][col=j]: lane holds d = ad*16+lg*4+{0..3}, j = wv*64+bj*16+lr
#pragma unroll
  for (int ad = 0; ad < 4; ++ad)
#pragma unroll
    for (int bj = 0; bj < 4; ++bj) {
      int j = wv * 64 + bj * 16 + lr;
      half4 o;
#pragma unroll
      for (int jj = 0; jj < 4; ++jj) o[jj] = (_Float16)acc[ad][bj][jj];
      *(half4*)(wdt + (size_t)b * 131072 + (size_t)j * 512 + hh * 64 + ad * 16 + lg * 4) = o;
    }
}

// ---------------- K3: out = q16 @ wdt[b] + b_out ----------------
__global__ void __launch_bounds__(256) k_out(const _Float16* __restrict__ q16,
                                             const _Float16* __restrict__ wdt,
                                             const float* __restrict__ bout,
                                             float* __restrict__ out) {
  __shared__ alignas(16) _Float16 qa[2][4096];     // [64 rows][64 K] 8 KB x2
  __shared__ alignas(16) _Float16 wtile[2][16384]; // [256 cols][64 K] 32 KB x2
  const int row0 = blockIdx.x * 64;
  const int b = row0 >> 13;
  const _Float16* wb = wdt + (size_t)b * 131072;
  const int t = threadIdx.x, wv = t >> 6, l = t & 63, lr = l & 15, lg = l >> 4;

  auto stage = [&](int buf, int kt) {
#pragma unroll
    for (int call = 0; call < 2; ++call) {
      int ob = (call * 4 + wv) * 1024;
      int o = ob + l * 16;
      int r = o >> 7;
      int kb = (o & 127) ^ ((r & 7) << 4);
      const char* src = (const char*)(q16 + (size_t)(row0 + r) * 512 + kt * 64) + kb;
      GLL(src, (char*)&qa[buf][0] + ob);
    }
#pragma unroll
    for (int call = 0; call < 8; ++call) {
      int ob = (call * 4 + wv) * 1024;
      int o = ob + l * 16;
      int c = o >> 7;
      int kb = (o & 127) ^ ((c & 7) << 4);
      const char* src = (const char*)(wb + (size_t)c * 512 + kt * 64) + kb;
      GLL(src, (char*)&wtile[buf][0] + ob);
    }
  };

  f32x4 acc[16] = {};
  stage(0, 0);
  __syncthreads();
#pragma unroll 1
  for (int kt = 0; kt < 8; ++kt) {
    int cur = kt & 1;
    if (kt < 7) stage(cur ^ 1, kt + 1);
    const int arow = wv * 16 + lr;
#pragma unroll
    for (int sp = 0; sp < 2; ++sp) {
      int kb = sp * 64 + lg * 16;
      half8 af = *(const half8*)((const char*)&qa[cur][0] + arow * 128 + (kb ^ ((arow & 7) << 4)));
#pragma unroll
      for (int cf = 0; cf < 16; ++cf) {
        int c = cf * 16 + lr;
        half8 bf = *(const half8*)((const char*)&wtile[cur][0] + c * 128 + (kb ^ ((c & 7) << 4)));
        acc[cf] = __builtin_amdgcn_mfma_f32_16x16x32_f16(af, bf, acc[cf], 0, 0, 0);
      }
    }
    __syncthreads();
  }
#pragma unroll
  for (int cf = 0; cf < 16; ++cf) {
    int col = cf * 16 + lr;
    float bo = bout[col];
#pragma unroll
    for (int j = 0; j < 4; ++j) {
      int grow = row0 + wv * 16 + lg * 4 + j;
      out[(size_t)grow * 256 + col] = acc[cf][j] + bo;
    }
  }
}

// ---------------- launch ----------------
extern "C" void kernel_launch(void* const* d_in, const int* in_sizes, int n_in,
                              void* d_out, int out_size, void* d_ws, size_t ws_size,
                              hipStream_t stream) {
  const float* x    = (const float*)d_in[0];
  const float* pos  = (const float*)d_in[1];
  const float* wqkv = (const float*)d_in[2];
  const float* wout = (const float*)d_in[3];
  const float* bout = (const float*)d_in[4];
  float* out = (float*)d_out;
  char* ws = (char*)d_ws;

  _Float16* wt16 = (_Float16*)(ws + 0);           //    786,432 B
  _Float16* q16  = (_Float16*)(ws + 786432);      // 33,554,432 B
  _Float16* k16  = (_Float16*)(ws + 34340864);    // 33,554,432 B
  _Float16* v16  = (_Float16*)(ws + 67895296);    // 33,554,432 B
  float*    part = (float*)   (ws + 101449728);   //  8,388,608 B
  _Float16* wdt  = (_Float16*)(ws + 109838336);   //  1,048,576 B (end 110,886,912)

  k_cvt_w<<<1536, 256, 0, stream>>>(wqkv, wt16);
  k_qkv<<<512, 256, 0, stream>>>(x, wt16, pos, q16, k16, v16);
  k_dots<<<dim3(16, 32), 256, 0, stream>>>(k16, v16, part);
  k_wd<<<32, 256, 0, stream>>>(part, wout, wdt);
  k_out<<<512, 256, 0, stream>>>(q16, wdt, bout, out);
}

// Round 4
// 106.136 us; speedup vs baseline: 2.2119x; 1.4101x over previous
//
#include <hip/hip_runtime.h>
#include <hip/hip_fp16.h>

#define BB 4
#define NN 8192
#define DD 256
#define HH 8
#define MM 32768   // BB*NN

typedef __attribute__((ext_vector_type(8))) _Float16 half8;
typedef __attribute__((ext_vector_type(4))) _Float16 half4;
typedef __attribute__((ext_vector_type(2))) _Float16 half2v;
typedef __attribute__((ext_vector_type(4))) float f32x4;

#define GLL(src, dst)                                                        \
  __builtin_amdgcn_global_load_lds(                                          \
      (const __attribute__((address_space(1))) void*)(src),                  \
      (__attribute__((address_space(3))) void*)(dst), 16, 0, 0)

// ---------------- K0: W conversion ----------------
// W_qkv [256][1536] fp32 -> Wt [1536][256] fp16 (transposed)
__global__ void __launch_bounds__(256) k_cvt_w(const float* __restrict__ w,
                                               _Float16* __restrict__ wt) {
  int idx = blockIdx.x * 256 + threadIdx.x;  // 0..393215
  int k = idx / 1536, c = idx % 1536;
  wt[(size_t)c * 256 + k] = (_Float16)w[idx];
}

// ---------------- K1: qkv GEMM + norm + rotary + fused dots-partial ----------------
// grid(512): 64 rows x 1536 cols, K=256. 4 waves.
// Per head: GEMM -> register epilogue -> q to global; k,v into the DEAD W buffer
// as kT[d][row]/vT[e][row] -> MFMA k^T v (K=64 rows) -> fp16 partial to global.
__global__ void __launch_bounds__(256) k_qkv(const float* __restrict__ x,
                                             const _Float16* __restrict__ wt,
                                             const float* __restrict__ pos,
                                             _Float16* __restrict__ q16,
                                             _Float16* __restrict__ part16) {
  __shared__ alignas(16) _Float16 xa[16384];      // [64 rows][256 K] swizzled, 32 KB
  __shared__ alignas(16) _Float16 wb[2][12288];   // [192 cols][64 K] swizzled, 24 KB x2
  const int row0 = blockIdx.x * 64;
  const int t = threadIdx.x;
  const int wv = t >> 6, l = t & 63, lr = l & 15, lg = l >> 4;

  // ---- stage x: fp32 -> fp16 into swizzled LDS (once per block) ----
#pragma unroll
  for (int it = 0; it < 8; ++it) {
    int o = it * 4096 + t * 16;                    // physical byte offset
    int row = o >> 9;
    int colb = (o & 511) ^ ((row & 7) << 4);       // logical col byte (XOR involution)
    const float* src = x + (size_t)(row0 + row) * 256 + (colb >> 1);
    float4 a = *(const float4*)src;
    float4 b = *(const float4*)(src + 4);
    half8 hv;
    hv[0] = (_Float16)a.x; hv[1] = (_Float16)a.y; hv[2] = (_Float16)a.z; hv[3] = (_Float16)a.w;
    hv[4] = (_Float16)b.x; hv[5] = (_Float16)b.y; hv[6] = (_Float16)b.z; hv[7] = (_Float16)b.w;
    *(half8*)((char*)xa + o) = hv;
  }

  // ---- hoist rotary angles: freq index = lg*4+j, row = wv*16+lr ----
  const int myrow = row0 + wv * 16 + lr;
  const float px = pos[(size_t)myrow * 2 + 0] * 64.0f;
  const float py = pos[(size_t)myrow * 2 + 1] * 64.0f;
  float sxj[4], cxj[4], syj[4], cyj[4];
#pragma unroll
  for (int j = 0; j < 4; ++j) {
    float invf = exp2f((float)(lg * 4 + j) * -0.8304820237218405f);  // 10000^(-fi/16)
    __sincosf(px * invf, &sxj[j], &cxj[j]);
    __sincosf(py * invf, &syj[j], &cyj[j]);
  }

  // ---- W staging: global_load_lds, pre-swizzled source ----
  auto stageW = [&](int buf, int hh, int kt) {
#pragma unroll
    for (int call = 0; call < 6; ++call) {
      int ob = (call * 4 + wv) * 1024;             // wave-uniform dest base (bytes)
      int o = ob + l * 16;                         // this lane's dest byte
      int c = o >> 7;                              // col 0..191
      int kb = (o & 127) ^ ((c & 7) << 4);         // logical K byte
      int gc = ((c >> 6) << 9) + (hh << 6) + (c & 63);  // global wt row
      const char* src = (const char*)(wt + (size_t)gc * 256 + kt * 64) + kb;
      GLL(src, (char*)&wb[buf][0] + ob);
    }
  };

  stageW(0, 0, 0);
  __syncthreads();

  int cur = 0;
#pragma unroll 1
  for (int h = 0; h < 8; ++h) {
    f32x4 acc[12] = {};
#pragma unroll 1
    for (int kt = 0; kt < 4; ++kt) {
      int ni = (h << 2) + kt + 1;
      if (ni < 32) stageW(cur ^ 1, ni >> 2, ni & 3);
      const int arow = wv * 16 + lr;
      const char* wbp = (const char*)&wb[cur][0];
#pragma unroll
      for (int sp = 0; sp < 2; ++sp) {
        int kbl = kt * 128 + sp * 64 + lg * 16;
        half8 af = *(const half8*)((const char*)xa + arow * 512 + (kbl ^ ((arow & 7) << 4)));
        int wkb = sp * 64 + lg * 16;
#pragma unroll
        for (int cf = 0; cf < 12; ++cf) {
          int c = cf * 16 + lr;
          half8 bf = *(const half8*)(wbp + c * 128 + (wkb ^ ((c & 7) << 4)));
          // SWAPPED: A = W fragment, B = x fragment -> D[wcol][xrow]
          acc[cf] = __builtin_amdgcn_mfma_f32_16x16x32_f16(bf, af, acc[cf], 0, 0, 0);
        }
      }
      __syncthreads();
      cur ^= 1;
    }
    // after 4 kt-flips: wb[cur] = next head's kt0 (prefetched); wb[cur^1] = DEAD.
    _Float16* dead = &wb[cur ^ 1][0];   // kT: [64 d][80 rows]; vT at +5120 halfs

    // ---- epilogue (register): lane holds cols lg*4+{0..3} of row lr ----
    float sk = 0.f, sk2 = 0.f, sv = 0.f, sv2 = 0.f;
#pragma unroll
    for (int cc = 4; cc < 12; ++cc)
#pragma unroll
      for (int j = 0; j < 4; ++j) {
        float u = acc[cc][j];
        if (cc < 8) { sk += u; sk2 += u * u; } else { sv += u; sv2 += u * u; }
      }
    sk += __shfl_xor(sk, 16, 64);  sk += __shfl_xor(sk, 32, 64);
    sk2 += __shfl_xor(sk2, 16, 64); sk2 += __shfl_xor(sk2, 32, 64);
    sv += __shfl_xor(sv, 16, 64);  sv += __shfl_xor(sv, 32, 64);
    sv2 += __shfl_xor(sv2, 16, 64); sv2 += __shfl_xor(sv2, 32, 64);
    float mk = sk * 0.015625f, mv = sv * 0.015625f;
    float ik = rsqrtf(sk2 * 0.015625f - mk * mk + 1e-5f);
    float iv = rsqrtf(sv2 * 0.015625f - mv * mv + 1e-5f);

    half4 oq[4], ok[4], ov[4];
#pragma unroll
    for (int j = 0; j < 4; ++j) {
      float q0 = acc[0][j], q1 = acc[1][j], q2 = acc[2][j], q3 = acc[3][j];
      oq[0][j] = (_Float16)(q0 * cxj[j] - q1 * sxj[j]);
      oq[1][j] = (_Float16)(q1 * cxj[j] + q0 * sxj[j]);
      oq[2][j] = (_Float16)(q2 * cyj[j] - q3 * syj[j]);
      oq[3][j] = (_Float16)(q3 * cyj[j] + q2 * syj[j]);
      float k0 = (acc[4][j] - mk) * ik, k1 = (acc[5][j] - mk) * ik;
      float k2 = (acc[6][j] - mk) * ik, k3 = (acc[7][j] - mk) * ik;
      ok[0][j] = (_Float16)(k0 * cxj[j] - k1 * sxj[j]);
      ok[1][j] = (_Float16)(k1 * cxj[j] + k0 * sxj[j]);
      ok[2][j] = (_Float16)(k2 * cyj[j] - k3 * syj[j]);
      ok[3][j] = (_Float16)(k3 * cyj[j] + k2 * syj[j]);
      ov[0][j] = (_Float16)((acc[8][j]  - mv) * iv);
      ov[1][j] = (_Float16)((acc[9][j]  - mv) * iv);
      ov[2][j] = (_Float16)((acc[10][j] - mv) * iv);
      ov[3][j] = (_Float16)((acc[11][j] - mv) * iv);
    }
    // q -> global
    size_t qbase = (size_t)myrow * 512 + h * 64 + lg * 4;
#pragma unroll
    for (int cc = 0; cc < 4; ++cc) *(half4*)(q16 + qbase + cc * 16) = oq[cc];
    // k,v -> dead buffer, transposed: kT[d][row], vT[e][row] (stride 80)
#pragma unroll
    for (int cc = 0; cc < 4; ++cc)
#pragma unroll
      for (int j = 0; j < 4; ++j) {
        int dr = (cc * 16 + lg * 4 + j) * 80 + wv * 16 + lr;
        dead[dr] = ok[cc][j];
        dead[5120 + dr] = ov[cc][j];
      }
    __syncthreads();

    // ---- dots partial: D[d][e] = sum_rows kT[d][row] vT[e][row], K=64 ----
    f32x4 dacc[4] = {};
#pragma unroll
    for (int ks = 0; ks < 2; ++ks) {
      half8 adf = *(const half8*)(dead + (wv * 16 + lr) * 80 + ks * 32 + lg * 8);
#pragma unroll
      for (int ep = 0; ep < 4; ++ep) {
        half8 bdf = *(const half8*)(dead + 5120 + (ep * 16 + lr) * 80 + ks * 32 + lg * 8);
        dacc[ep] = __builtin_amdgcn_mfma_f32_16x16x32_f16(adf, bdf, dacc[ep], 0, 0, 0);
      }
    }
    __syncthreads();   // protect dead buffer from next head's prefetch
    // partial layout [e][d]: lane holds d = wv*16 + lg*4+{0..3}, e = ep*16+lr
    _Float16* pdst = part16 + ((size_t)blockIdx.x * 8 + h) * 4096;
#pragma unroll
    for (int ep = 0; ep < 4; ++ep) {
      half4 o;
#pragma unroll
      for (int j = 0; j < 4; ++j) o[j] = (_Float16)dacc[ep][j];
      *(half4*)(pdst + (ep * 16 + lr) * 64 + wv * 16 + lg * 4) = o;
    }
  }
}

// ---------------- K2: reduce 512 rowtile partials -> dots fp32 [32 bh][e*64+d] ----
// grid(256): bh = blockIdx>>3, slice = blockIdx&7 (512 halfs each). 2 halfs/thread.
__global__ void __launch_bounds__(256) k_pred(const _Float16* __restrict__ part16,
                                              float* __restrict__ dots) {
  const int bh = blockIdx.x >> 3, sl = blockIdx.x & 7;
  const int b = bh >> 3, h = bh & 7;
  const int idx = sl * 512 + threadIdx.x * 2;
  const _Float16* base = part16 + ((size_t)(b * 128) * 8 + h) * 4096 + idx;
  float s0 = 0.f, s1 = 0.f;
#pragma unroll 4
  for (int rt = 0; rt < 128; ++rt) {
    half2v v = *(const half2v*)(base + (size_t)rt * 32768);
    s0 += (float)v[0]; s1 += (float)v[1];
  }
  dots[(size_t)bh * 4096 + idx] = s0;
  dots[(size_t)bh * 4096 + idx + 1] = s1;
}

// ---------------- K2b: wdt[b][j][h*64+d] = (1/N) sum_e dotsT[e][d] wout[h*64+e][j]
// grid(32): bid = b*8+h. dots input is [e][d] orientation.
__global__ void __launch_bounds__(256) k_wd(const float* __restrict__ dots,
                                            const float* __restrict__ wout,
                                            _Float16* __restrict__ wdt) {
  __shared__ alignas(16) _Float16 a_lds[4096];    // [64 d][64 e] swizzled, 8 KB
  __shared__ alignas(16) _Float16 b_lds[16384];   // [256 j][64 e] swizzled, 32 KB
  const int bid = blockIdx.x, b = bid >> 3, hh = bid & 7;
  const int t = threadIdx.x, wv = t >> 6, l = t & 63, lr = l & 15, lg = l >> 4;

  // A: dots [e][d] fp32 -> a_lds [d][e] fp16 (scaled)
#pragma unroll
  for (int g = 0; g < 4; ++g) {
    int i4 = (g * 256 + t) * 4;  // 0..4095, e = i4>>6, d = i4&63
    f32x4 s = *(const f32x4*)(dots + (size_t)bid * 4096 + i4);
    int e = i4 >> 6, d0 = i4 & 63;
#pragma unroll
    for (int m = 0; m < 4; ++m) {
      int d = d0 + m;
      *(_Float16*)((char*)a_lds + d * 128 + ((e * 2) ^ ((d & 7) << 4))) =
          (_Float16)(s[m] * (1.0f / 8192.0f));
    }
  }
  // B: wout rows hh*64..+63, transposed to [j][e] fp16
#pragma unroll
  for (int g = 0; g < 16; ++g) {
    int i4 = (g * 256 + t) * 4;  // 0..16383
    int e = i4 >> 8, j0 = i4 & 255;
    f32x4 u = *(const f32x4*)(wout + (size_t)(hh * 64 + e) * 256 + j0);
#pragma unroll
    for (int m = 0; m < 4; ++m) {
      int j = j0 + m;
      *(_Float16*)((char*)b_lds + j * 128 + ((e * 2) ^ ((j & 7) << 4))) = (_Float16)u[m];
    }
  }
  __syncthreads();

  f32x4 acc[4][4] = {};
#pragma unroll
  for (int sp = 0; sp < 2; ++sp) {
    int kb = sp * 64 + lg * 16;
    half8 af[4], bf[4];
#pragma unroll
    for (int ad = 0; ad < 4; ++ad) {
      int d = ad * 16 + lr;
      af[ad] = *(const half8*)((const char*)a_lds + d * 128 + (kb ^ ((d & 7) << 4)));
    }
#pragma unroll
    for (int bj = 0; bj < 4; ++bj) {
      int j = wv * 64 + bj * 16 + lr;
      bf[bj] = *(const half8*)((const char*)b_lds + j * 128 + (kb ^ ((j & 7) << 4)));
    }
#pragma unroll
    for (int ad = 0; ad < 4; ++ad)
#pragma unroll
      for (int bj = 0; bj < 4; ++bj)
        acc[ad][bj] = __builtin_amdgcn_mfma_f32_16x16x32_f16(af[ad], bf[bj], acc[ad][bj], 0, 0, 0);
  }
  // D[row=d][col=j]: lane holds d = ad*16+lg*4+{0..3}, j = wv*64+bj*16+lr
#pragma unroll
  for (int ad = 0; ad < 4; ++ad)
#pragma unroll
    for (int bj = 0; bj < 4; ++bj) {
      int j = wv * 64 + bj * 16 + lr;
      half4 o;
#pragma unroll
      for (int jj = 0; jj < 4; ++jj) o[jj] = (_Float16)acc[ad][bj][jj];
      *(half4*)(wdt + (size_t)b * 131072 + (size_t)j * 512 + hh * 64 + ad * 16 + lg * 4) = o;
    }
}

// ---------------- K3: out = q16 @ wdt[b] + b_out ----------------
__global__ void __launch_bounds__(256) k_out(const _Float16* __restrict__ q16,
                                             const _Float16* __restrict__ wdt,
                                             const float* __restrict__ bout,
                                             float* __restrict__ out) {
  __shared__ alignas(16) _Float16 qa[2][4096];     // [64 rows][64 K] 8 KB x2
  __shared__ alignas(16) _Float16 wtile[2][16384]; // [256 cols][64 K] 32 KB x2
  const int row0 = blockIdx.x * 64;
  const int b = row0 >> 13;
  const _Float16* wb = wdt + (size_t)b * 131072;
  const int t = threadIdx.x, wv = t >> 6, l = t & 63, lr = l & 15, lg = l >> 4;

  auto stage = [&](int buf, int kt) {
#pragma unroll
    for (int call = 0; call < 2; ++call) {
      int ob = (call * 4 + wv) * 1024;
      int o = ob + l * 16;
      int r = o >> 7;
      int kb = (o & 127) ^ ((r & 7) << 4);
      const char* src = (const char*)(q16 + (size_t)(row0 + r) * 512 + kt * 64) + kb;
      GLL(src, (char*)&qa[buf][0] + ob);
    }
#pragma unroll
    for (int call = 0; call < 8; ++call) {
      int ob = (call * 4 + wv) * 1024;
      int o = ob + l * 16;
      int c = o >> 7;
      int kb = (o & 127) ^ ((c & 7) << 4);
      const char* src = (const char*)(wb + (size_t)c * 512 + kt * 64) + kb;
      GLL(src, (char*)&wtile[buf][0] + ob);
    }
  };

  f32x4 acc[16] = {};
  stage(0, 0);
  __syncthreads();
#pragma unroll 1
  for (int kt = 0; kt < 8; ++kt) {
    int cur = kt & 1;
    if (kt < 7) stage(cur ^ 1, kt + 1);
    const int arow = wv * 16 + lr;
#pragma unroll
    for (int sp = 0; sp < 2; ++sp) {
      int kb = sp * 64 + lg * 16;
      half8 af = *(const half8*)((const char*)&qa[cur][0] + arow * 128 + (kb ^ ((arow & 7) << 4)));
#pragma unroll
      for (int cf = 0; cf < 16; ++cf) {
        int c = cf * 16 + lr;
        half8 bf = *(const half8*)((const char*)&wtile[cur][0] + c * 128 + (kb ^ ((c & 7) << 4)));
        acc[cf] = __builtin_amdgcn_mfma_f32_16x16x32_f16(af, bf, acc[cf], 0, 0, 0);
      }
    }
    __syncthreads();
  }
#pragma unroll
  for (int cf = 0; cf < 16; ++cf) {
    int col = cf * 16 + lr;
    float bo = bout[col];
#pragma unroll
    for (int j = 0; j < 4; ++j) {
      int grow = row0 + wv * 16 + lg * 4 + j;
      out[(size_t)grow * 256 + col] = acc[cf][j] + bo;
    }
  }
}

// ---------------- launch ----------------
extern "C" void kernel_launch(void* const* d_in, const int* in_sizes, int n_in,
                              void* d_out, int out_size, void* d_ws, size_t ws_size,
                              hipStream_t stream) {
  const float* x    = (const float*)d_in[0];
  const float* pos  = (const float*)d_in[1];
  const float* wqkv = (const float*)d_in[2];
  const float* wout = (const float*)d_in[3];
  const float* bout = (const float*)d_in[4];
  float* out = (float*)d_out;
  char* ws = (char*)d_ws;

  _Float16* wt16   = (_Float16*)(ws + 0);          //    786,432 B
  _Float16* q16    = (_Float16*)(ws + 786432);     // 33,554,432 B
  _Float16* part16 = (_Float16*)(ws + 34340864);   // 33,554,432 B
  float*    dots   = (float*)   (ws + 67895296);   //    524,288 B
  _Float16* wdt    = (_Float16*)(ws + 68419584);   //  1,048,576 B (end 69,468,160)

  k_cvt_w<<<1536, 256, 0, stream>>>(wqkv, wt16);
  k_qkv<<<512, 256, 0, stream>>>(x, wt16, pos, q16, part16);
  k_pred<<<256, 256, 0, stream>>>(part16, dots);
  k_wd<<<32, 256, 0, stream>>>(dots, wout, wdt);
  k_out<<<512, 256, 0, stream>>>(q16, wdt, bout, out);
}